// Round 6
// baseline (61.842 us; speedup 1.0000x reference)
//
#include <hip/hip_runtime.h>
#include <hip/hip_bf16.h>

// out[b, d] = remap_phase(W[labels[b], d] + noise[b, d])
// remap_phase(x) = mod(x + 1, 2) - 1   (wrap into [-1, 1))
//
// B = 262144, D = 128, N_CLASSES = 100000. fp32 data, int32 labels.
// Compulsory HBM/call: noise 134MB + out 134MB + labels 1MB; W (51MB)
// L3-resident -> roofline ~43us @ 6.3 TB/s mixed-stream.
//
// History:
//  R1: grid-stride, VGPR=8, occ 76%, 65.8us — latency-bound, MLP~2.
//  R3: unroll x8 strided, i64 idx + bounds -> VGPR=208, occ 11%, 181.8us.
//  R4: per-thread-contiguous 64B -> per-instruction stride ->
//      WRITE_SIZE 131->236MB write amplification, 134.6us.
//  R5: block-contiguous lane-consecutive ITERS=4, VGPR~40: 61.5us
//      (4.4 TB/s; poison-fill calibration: pure writes hit 7.1 TB/s).
//  R6 (this): same mapping, ITERS=8, int indices, exact-fit grid (no
//      bounds): 8 W + 8 noise loads in flight; VGPR ~100 -> occ ~50%.
//      MLP (occ x depth) up ~1.4x. Predict ~50-55us.

typedef float f32x4 __attribute__((ext_vector_type(4)));

constexpr int ITERS = 8;

__global__ void __launch_bounds__(256) label_encoder_kernel(
    const int* __restrict__ labels,
    const float* __restrict__ W,       // [N_CLASSES, 128]
    const float* __restrict__ noise,   // [B, 128]
    float* __restrict__ out)           // [B, 128]
{
    // block owns float4 range [blk*2048, blk*2048 + 2048) = 64 rows.
    // iteration i: g = blk*2048 + i*256 + tid -> lanes consecutive
    // within each instruction (1KB contiguous per wave access).
    const int tid = threadIdx.x;
    const int g0  = blockIdx.x * (256 * ITERS) + tid;

    int lab[ITERS];
    #pragma unroll
    for (int i = 0; i < ITERS; ++i)
        lab[i] = labels[(g0 + i * 256) >> 5];   // 32 lanes share a label

    f32x4 nz[ITERS], w[ITERS];
    #pragma unroll
    for (int i = 0; i < ITERS; ++i)
        nz[i] = __builtin_nontemporal_load(
            reinterpret_cast<const f32x4*>(noise) + (g0 + i * 256));
    #pragma unroll
    for (int i = 0; i < ITERS; ++i)
        w[i] = *(reinterpret_cast<const f32x4*>(W)
                 + (long long)lab[i] * 32 + ((g0 + i * 256) & 31));

    #pragma unroll
    for (int i = 0; i < ITERS; ++i) {
        f32x4 r;
        #pragma unroll
        for (int j = 0; j < 4; ++j) {
            float y = w[i][j] + nz[i][j] + 1.0f;
            r[j] = y - 2.0f * floorf(y * 0.5f) - 1.0f;
        }
        __builtin_nontemporal_store(
            r, reinterpret_cast<f32x4*>(out) + (g0 + i * 256));
    }
}

extern "C" void kernel_launch(void* const* d_in, const int* in_sizes, int n_in,
                              void* d_out, int out_size, void* d_ws, size_t ws_size,
                              hipStream_t stream) {
    const int*   labels = (const int*)d_in[0];    // [B]
    const float* W      = (const float*)d_in[1];  // [N_CLASSES, 128]
    const float* noise  = (const float*)d_in[2];  // [B, 128]
    float*       out    = (float*)d_out;          // [B, 128]

    // out_size = 33554432 floats = 8388608 float4; 2048 float4 per block.
    const int block = 256;
    const int grid  = (int)((long long)out_size / 4 / (block * ITERS)); // 4096
    label_encoder_kernel<<<grid, block, 0, stream>>>(labels, W, noise, out);
}